// Round 7
// baseline (474.386 us; speedup 1.0000x reference)
//
#include <hip/hip_runtime.h>
#include <cstdint>

// GraphNets v7: column-parallel MFMA MLP, B-frags register-stationary.
// mfma_f32_16x16x32_bf16: A lane l: row=l&15, k=(l>>4)*8+j ; B: col=l&15, same k
// C/D: col=lane&15, row=(lane>>4)*4+reg   [verified v2-v6]

typedef short short8 __attribute__((ext_vector_type(8)));
typedef float f32x4 __attribute__((ext_vector_type(4)));

#define MFMA16(a, b, c) __builtin_amdgcn_mfma_f32_16x16x32_bf16(a, b, c, 0, 0, 0)

__device__ __forceinline__ short f2bf(float x) {
    union { __bf16 b; short s; } u; u.b = (__bf16)x; return u.s;
}
__device__ __forceinline__ short8 pack8(float4 lo, float4 hi) {
    short8 r;
    r[0] = f2bf(lo.x); r[1] = f2bf(lo.y); r[2] = f2bf(lo.z); r[3] = f2bf(lo.w);
    r[4] = f2bf(hi.x); r[5] = f2bf(hi.y); r[6] = f2bf(hi.z); r[7] = f2bf(hi.w);
    return r;
}
__device__ __forceinline__ short8 pack8v(f32x4 lo, f32x4 hi) {
    short8 r;
    r[0] = f2bf(lo[0]); r[1] = f2bf(lo[1]); r[2] = f2bf(lo[2]); r[3] = f2bf(lo[3]);
    r[4] = f2bf(hi[0]); r[5] = f2bf(hi[1]); r[6] = f2bf(hi[2]); r[7] = f2bf(hi[3]);
    return r;
}

// ---------------------------------------------------------------------------
// Weight prep: fp32 [K][N] -> bf16 B-fragments (frag kf*NF+nf, 1024B each,
// lane-contiguous). Offsets: We1 0 | We2 65536 | We3 98304 | Wn1 114688 |
// Wn2 163840 | Wn3 196608.   (verified v2-v6)
// ---------------------------------------------------------------------------
__global__ __launch_bounds__(256)
void prep_weights(const float* __restrict__ We1, const float* __restrict__ We2,
                  const float* __restrict__ We3, const float* __restrict__ Wn1,
                  const float* __restrict__ Wn2, const float* __restrict__ Wn3,
                  char* __restrict__ out)
{
    const int fg = blockIdx.x * 4 + (threadIdx.x >> 6);
    if (fg >= 208) return;
    const int lane = threadIdx.x & 63;
    const float* W; int Ncols, f; size_t obase;
    if      (fg < 64)  { W = We1; Ncols = 128; f = fg;       obase = 0;      }
    else if (fg < 96)  { W = We2; Ncols = 128; f = fg - 64;  obase = 65536;  }
    else if (fg < 112) { W = We3; Ncols = 64;  f = fg - 96;  obase = 98304;  }
    else if (fg < 160) { W = Wn1; Ncols = 128; f = fg - 112; obase = 114688; }
    else if (fg < 192) { W = Wn2; Ncols = 128; f = fg - 160; obase = 163840; }
    else               { W = Wn3; Ncols = 64;  f = fg - 192; obase = 196608; }
    const int NF = Ncols >> 4;
    const int kf = f / NF, nf = f - kf * NF;
    const int k0 = kf * 32 + (lane >> 4) * 8;
    const int col = nf * 16 + (lane & 15);
    union { short s[8]; uint4 u; } pk;
#pragma unroll
    for (int j = 0; j < 8; ++j) pk.s[j] = f2bf(W[(size_t)(k0 + j) * Ncols + col]);
    *(uint4*)(out + obase + ((size_t)f * 64 + lane) * 16) = pk.u;
}

// ---------------------------------------------------------------------------
// CSR build (verified v4)
// ---------------------------------------------------------------------------
__global__ __launch_bounds__(256)
void hist_kernel(const int* __restrict__ dst, int* __restrict__ deg, int E)
{
    const int i = blockIdx.x * 256 + threadIdx.x;
    if (i < E) atomicAdd(&deg[dst[i]], 1);
}
__global__ __launch_bounds__(256)
void scanA_kernel(const int* __restrict__ deg, int* __restrict__ psum, int n)
{
    __shared__ int red[256];
    const int t = threadIdx.x;
    const int i = blockIdx.x * 256 + t;
    red[t] = (i < n) ? deg[i] : 0;
    __syncthreads();
    for (int s = 128; s > 0; s >>= 1) {
        if (t < s) red[t] += red[t + s];
        __syncthreads();
    }
    if (t == 0) psum[blockIdx.x] = red[0];
}
__global__ __launch_bounds__(256)
void scanB_kernel(int* __restrict__ psum, int nb)
{
    __shared__ int s[256];
    const int t = threadIdx.x;
    const int v0 = (t < nb) ? psum[t] : 0;
    s[t] = v0;
    __syncthreads();
    for (int d = 1; d < 256; d <<= 1) {
        const int v = (t >= d) ? s[t - d] : 0;
        __syncthreads();
        s[t] += v;
        __syncthreads();
    }
    if (t < nb) psum[t] = s[t] - v0;
}
__global__ __launch_bounds__(256)
void scanC_kernel(const int* __restrict__ deg, const int* __restrict__ psum,
                  int* __restrict__ start, int* __restrict__ cursor, int n)
{
    __shared__ int s[256];
    const int t = threadIdx.x;
    const int i = blockIdx.x * 256 + t;
    const int v0 = (i < n) ? deg[i] : 0;
    s[t] = v0;
    __syncthreads();
    for (int d = 1; d < 256; d <<= 1) {
        const int v = (t >= d) ? s[t - d] : 0;
        __syncthreads();
        s[t] += v;
        __syncthreads();
    }
    const int ex = s[t] - v0 + psum[blockIdx.x];
    if (i < n) { start[i] = ex; cursor[i] = ex; }
}
__global__ __launch_bounds__(256)
void fill_kernel(const int* __restrict__ dst, int* __restrict__ cursor,
                 int* __restrict__ elist, int E)
{
    const int i = blockIdx.x * 256 + threadIdx.x;
    if (i < E) {
        const int d = dst[i];
        const int p = atomicAdd(&cursor[d], 1);
        elist[p] = i;
    }
}

// ---------------------------------------------------------------------------
// v7 column-parallel MLP. Block = 512 thr = 8 waves; tile = 64 rows.
// Wave w owns output cols [w*16, w*16+16) for layers 1-2 (B-frags in REGS);
// layer 3: nf3 = w&3, row-half = w>>2; W3 from LDS.
// LDS: X (64 x NQ*128B, swizzled) | h1 (16KB) | W3 (16KB) | comb (4KB).
// h2 reuses X[0:16KB]. 4 barriers per tile. 2 blocks/CU.
// ---------------------------------------------------------------------------
template <int NQ, bool IS_EDGE, bool MSG_ATOMIC, bool GATHER>
__global__ __launch_bounds__(512, 4)
void mlp_col_kernel(const float* __restrict__ feat0,
                    const float* feat1,
                    const float* __restrict__ gr,
                    const int* __restrict__ srcIdx, const int* __restrict__ dstIdx,
                    const int* __restrict__ seg,
                    const int* __restrict__ gstart, const int* __restrict__ gend,
                    const int* __restrict__ elist,  const float* __restrict__ gsrc,
                    const char* __restrict__ W1g, const char* __restrict__ W2g,
                    const char* __restrict__ W3g,
                    const float* __restrict__ b1, const float* __restrict__ b2,
                    const float* __restrict__ b3,
                    float* out, float* msgs_out, float* comb_rep,
                    int M, int ntiles)
{
    constexpr int KF1   = NQ * 2;          // layer-1 K fragments
    constexpr int XROWB = NQ * 128;        // X row bytes (bf16)
    constexpr int XSZ   = 64 * XROWB;
    extern __shared__ char lds[];
    char*  Xs    = lds;                    // X, later h2 in [0,16384)
    char*  H1s   = lds + XSZ;              // 16 KB
    char*  W3l   = lds + XSZ + 16384;      // 16 KB
    float* combs = (float*)(lds + XSZ + 32768);   // 4 KB

    const int t    = threadIdx.x;
    const int lane = t & 63;
    const int w    = t >> 6;
    const int l15  = lane & 15;
    const int l4   = lane >> 4;

    // ---- one-time: W3 -> LDS, comb zero, B1/B2 -> registers ----
    for (int f = t; f < 1024; f += 512)
        *(uint4*)(W3l + (size_t)f * 16) = *(const uint4*)(W3g + (size_t)f * 16);
    for (int i = t; i < 1024; i += 512) combs[i] = 0.f;

    short8 B1[KF1];
#pragma unroll
    for (int kf = 0; kf < KF1; ++kf)
        B1[kf] = *(const short8*)(W1g + ((size_t)(kf * 8 + w) * 64 + lane) * 16);
    short8 B2[4];
#pragma unroll
    for (int kf = 0; kf < 4; ++kf)
        B2[kf] = *(const short8*)(W2g + ((size_t)(kf * 8 + w) * 64 + lane) * 16);

    const float bv1 = b1[w * 16 + l15];
    const float bv2 = b2[w * 16 + l15];
    const int   nf3 = w & 3, rhalf = w >> 2;
    const float bv3 = b3[nf3 * 16 + l15];

    const int r   = t >> 3;        // staging: row 0..63
    const int sub = t & 7;         // staging: sub-chunk role
    __syncthreads();

    for (int tile = blockIdx.x; tile < ntiles; tile += gridDim.x) {
        const int tb = tile * 64;

        // ================= stage X (cooperative, 8 threads/row) =============
        {
            const int grow = tb + r;
            const bool v = grow < M;
            if (IS_EDGE) {
                // sub: c = sub>>1 (0 ef,1 src,2 dst,3 g), half = sub&1 (32 f32)
                const int c = sub >> 1, hf = sub & 1;
                float4 x[8];
#pragma unroll
                for (int i = 0; i < 8; ++i) x[i] = make_float4(0.f, 0.f, 0.f, 0.f);
                if (v) {
                    int idx = (c == 0) ? grow
                            : (c == 1) ? srcIdx[grow]
                            : (c == 2) ? dstIdx[grow] : seg[grow];
                    const float* p = ((c == 0) ? feat0 : (c == 3) ? gr : feat1)
                                     + (size_t)idx * 64 + hf * 32;
#pragma unroll
                    for (int i = 0; i < 8; ++i) x[i] = ((const float4*)p)[i];
                }
                const int s0 = sub * 4;
#pragma unroll
                for (int i = 0; i < 4; ++i)
                    *(short8*)(Xs + r * XROWB + ((s0 + i) ^ (r & 7)) * 16) =
                        pack8(x[2 * i], x[2 * i + 1]);
            } else {
                if (sub < 2) {                       // node_feat halves
                    float4 x[8];
#pragma unroll
                    for (int i = 0; i < 8; ++i) x[i] = make_float4(0.f, 0.f, 0.f, 0.f);
                    if (v) {
                        const float* p = feat0 + (size_t)grow * 64 + sub * 32;
#pragma unroll
                        for (int i = 0; i < 8; ++i) x[i] = ((const float4*)p)[i];
                    }
                    const int s0 = sub * 4;
#pragma unroll
                    for (int i = 0; i < 4; ++i)
                        *(short8*)(Xs + r * XROWB + ((s0 + i) ^ (r & 7)) * 16) =
                            pack8(x[2 * i], x[2 * i + 1]);
                } else if (sub < 6) {                // msgs, 16 cols each
                    const int c0 = (sub - 2) * 16;
                    f32x4 m0 = {0,0,0,0}, m1 = m0, m2 = m0, m3 = m0;
                    if (v) {
                        if constexpr (GATHER) {
                            const int s0i = gstart[grow], e0i = gend[grow];
                            for (int j = s0i; j < e0i; ++j) {
                                const float* er = gsrc + (size_t)elist[j] * 64 + c0;
                                m0 += *(const f32x4*)(er);
                                m1 += *(const f32x4*)(er + 4);
                                m2 += *(const f32x4*)(er + 8);
                                m3 += *(const f32x4*)(er + 12);
                            }
                        } else {
                            const float* er = feat1 + (size_t)grow * 64 + c0;
                            m0 = *(const f32x4*)(er);
                            m1 = *(const f32x4*)(er + 4);
                            m2 = *(const f32x4*)(er + 8);
                            m3 = *(const f32x4*)(er + 12);
                        }
                    }
                    const int s0 = 8 + (sub - 2) * 2;
                    *(short8*)(Xs + r * XROWB + ((s0    ) ^ (r & 7)) * 16) = pack8v(m0, m1);
                    *(short8*)(Xs + r * XROWB + ((s0 + 1) ^ (r & 7)) * 16) = pack8v(m2, m3);
                } else {                             // g_repr halves
                    float4 x[8];
#pragma unroll
                    for (int i = 0; i < 8; ++i) x[i] = make_float4(0.f, 0.f, 0.f, 0.f);
                    if (v) {
                        const float* p = gr + (size_t)seg[grow] * 64 + (sub - 6) * 32;
#pragma unroll
                        for (int i = 0; i < 8; ++i) x[i] = ((const float4*)p)[i];
                    }
                    const int s0 = 16 + (sub - 6) * 4;
#pragma unroll
                    for (int i = 0; i < 4; ++i)
                        *(short8*)(Xs + r * XROWB + ((s0 + i) ^ (r & 7)) * 16) =
                            pack8(x[2 * i], x[2 * i + 1]);
                }
            }
        }
        __syncthreads();                 // (1) X ready

        // ================= layer 1: acc[rf] over 64 rows, my 16 cols ========
        f32x4 acc[4];
#pragma unroll
        for (int rf = 0; rf < 4; ++rf) acc[rf] = f32x4{bv1, bv1, bv1, bv1};
#pragma unroll
        for (int kf = 0; kf < KF1; ++kf) {
#pragma unroll
            for (int rf = 0; rf < 4; ++rf) {
                short8 a = *(short8*)(Xs + (rf * 16 + l15) * XROWB +
                                      (((kf * 4 + l4) ^ (l15 & 7)) * 16));
                acc[rf] = MFMA16(a, B1[kf], acc[rf]);
            }
        }
        // relu -> h1 [row][128 cols, swizzled 16B slots]
#pragma unroll
        for (int rf = 0; rf < 4; ++rf)
#pragma unroll
            for (int q = 0; q < 4; ++q) {
                const int row = rf * 16 + l4 * 4 + q;
                const int slot = (w * 2 + (l15 >> 3)) ^ (row & 7);
                *(short*)(H1s + row * 256 + slot * 16 + (l15 & 7) * 2) =
                    f2bf(fmaxf(acc[rf][q], 0.f));
            }
        __syncthreads();                 // (2) h1 ready; X dead

        // ================= layer 2 =========================================
        f32x4 acc2[4];
#pragma unroll
        for (int rf = 0; rf < 4; ++rf) acc2[rf] = f32x4{bv2, bv2, bv2, bv2};
#pragma unroll
        for (int kf = 0; kf < 4; ++kf) {
#pragma unroll
            for (int rf = 0; rf < 4; ++rf) {
                short8 a = *(short8*)(H1s + (rf * 16 + l15) * 256 +
                                      (((kf * 4 + l4) ^ (l15 & 7)) * 16));
                acc2[rf] = MFMA16(a, B2[kf], acc2[rf]);
            }
        }
        // relu -> h2 (reuses X region, stride 256B)
#pragma unroll
        for (int rf = 0; rf < 4; ++rf)
#pragma unroll
            for (int q = 0; q < 4; ++q) {
                const int row = rf * 16 + l4 * 4 + q;
                const int slot = (w * 2 + (l15 >> 3)) ^ (row & 7);
                *(short*)(Xs + row * 256 + slot * 16 + (l15 & 7) * 2) =
                    f2bf(fmaxf(acc2[rf][q], 0.f));
            }
        __syncthreads();                 // (3) h2 ready

        // ================= layer 3: nf3 cols, row-half rhalf ===============
        f32x4 acc3[2];
        acc3[0] = f32x4{bv3, bv3, bv3, bv3};
        acc3[1] = acc3[0];
#pragma unroll
        for (int kf = 0; kf < 4; ++kf) {
            short8 bw = *(const short8*)(W3l + ((size_t)(kf * 4 + nf3) * 64 + lane) * 16);
#pragma unroll
            for (int rfi = 0; rfi < 2; ++rfi) {
                const int row = (rhalf * 2 + rfi) * 16 + l15;
                short8 a = *(short8*)(Xs + row * 256 +
                                      (((kf * 4 + l4) ^ (l15 & 7)) * 16));
                acc3[rfi] = MFMA16(a, bw, acc3[rfi]);
            }
        }

        // ================= epilogue ========================================
#pragma unroll
        for (int rfi = 0; rfi < 2; ++rfi)
#pragma unroll
            for (int q = 0; q < 4; ++q) {
                const int grow = tb + (rhalf * 2 + rfi) * 16 + l4 * 4 + q;
                if (grow < M) {
                    const int g = seg[grow];
                    const int col = nf3 * 16 + l15;
                    const float v = acc3[rfi][q];
                    out[(size_t)grow * 64 + col] = v;
                    if constexpr (MSG_ATOMIC)
                        atomicAdd(msgs_out + (size_t)dstIdx[grow] * 64 + col, v);
                    atomicAdd(&combs[g * 64 + col], v);
                }
            }
        __syncthreads();                 // (4) h2 readers done -> X reusable
    }

    float* rep = comb_rep + (size_t)(blockIdx.x & 63) * 1024;
    for (int i = t; i < 1024; i += 512) atomicAdd(rep + i, combs[i]);
}

// ---------------------------------------------------------------------------
__global__ __launch_bounds__(256)
void reduce_rep_kernel(const float* __restrict__ rep, float* __restrict__ outv)
{
    const int s = blockIdx.x * 256 + threadIdx.x;   // 0..2047
    const int arr = s >> 10, idx = s & 1023;
    const float* p = rep + (size_t)arr * 65536 + idx;
    float v = 0.f;
#pragma unroll 8
    for (int rr = 0; rr < 64; ++rr) v += p[(size_t)rr * 1024];
    outv[s] = v;
}

// ---------------------------------------------------------------------------
__global__ __launch_bounds__(256)
void u_kernel(const float* __restrict__ ncomb, const float* __restrict__ ecomb,
              const float* __restrict__ gr,
              const float* __restrict__ W1, const float* __restrict__ b1,
              const float* __restrict__ W2, const float* __restrict__ b2,
              const float* __restrict__ W3, const float* __restrict__ b3,
              float* uout)
{
    __shared__ float X[16 * 192];
    __shared__ float Hs[16 * 128];
    __shared__ float H2s[16 * 128];
    const int t = threadIdx.x;
#pragma unroll
    for (int i = 0; i < 12; ++i) {
        const int idx = i * 256 + t;
        const int g = idx / 192, col = idx % 192;
        float v;
        if      (col < 64)  v = ncomb[g * 64 + col];
        else if (col < 128) v = ecomb[g * 64 + col - 64];
        else                v = gr[g * 64 + col - 128];
        X[idx] = v;
    }
    __syncthreads();
    {
        const int j = t & 127, gb = t >> 7;
        float a[8];
#pragma unroll
        for (int gi = 0; gi < 8; ++gi) a[gi] = b1[j];
        for (int k = 0; k < 192; ++k) {
            const float wv = W1[k * 128 + j];
#pragma unroll
            for (int gi = 0; gi < 8; ++gi) a[gi] += X[(gb + gi * 2) * 192 + k] * wv;
        }
#pragma unroll
        for (int gi = 0; gi < 8; ++gi) Hs[(gb + gi * 2) * 128 + j] = fmaxf(a[gi], 0.f);
    }
    __syncthreads();
    {
        const int j = t & 127, gb = t >> 7;
        float a[8];
#pragma unroll
        for (int gi = 0; gi < 8; ++gi) a[gi] = b2[j];
        for (int k = 0; k < 128; ++k) {
            const float wv = W2[k * 128 + j];
#pragma unroll
            for (int gi = 0; gi < 8; ++gi) a[gi] += Hs[(gb + gi * 2) * 128 + k] * wv;
        }
#pragma unroll
        for (int gi = 0; gi < 8; ++gi) H2s[(gb + gi * 2) * 128 + j] = fmaxf(a[gi], 0.f);
    }
    __syncthreads();
    {
        const int j = t & 63, gb = t >> 6;
        float a[4];
#pragma unroll
        for (int gi = 0; gi < 4; ++gi) a[gi] = b3[j];
        for (int k = 0; k < 128; ++k) {
            const float wv = W3[k * 64 + j];
#pragma unroll
            for (int gi = 0; gi < 4; ++gi) a[gi] += H2s[(gb + gi * 4) * 128 + k] * wv;
        }
#pragma unroll
        for (int gi = 0; gi < 4; ++gi) uout[(gb + gi * 4) * 64 + j] = a[gi];
    }
}

// ---------------------------------------------------------------------------
extern "C" void kernel_launch(void* const* d_in, const int* in_sizes, int n_in,
                              void* d_out, int out_size, void* d_ws, size_t ws_size,
                              hipStream_t stream)
{
    const float* edge_feat = (const float*)d_in[0];
    const float* node_feat = (const float*)d_in[1];
    const float* g_repr    = (const float*)d_in[2];
    const int*   src       = (const int*)d_in[3];
    const int*   dst       = (const int*)d_in[4];
    const int*   e2g       = (const int*)d_in[5];
    const int*   n2g       = (const int*)d_in[6];
    const float* We1 = (const float*)d_in[7];  const float* be1 = (const float*)d_in[8];
    const float* We2 = (const float*)d_in[9];  const float* be2 = (const float*)d_in[10];
    const float* We3 = (const float*)d_in[11]; const float* be3 = (const float*)d_in[12];
    const float* Wn1 = (const float*)d_in[13]; const float* bn1 = (const float*)d_in[14];
    const float* Wn2 = (const float*)d_in[15]; const float* bn2 = (const float*)d_in[16];
    const float* Wn3 = (const float*)d_in[17]; const float* bn3 = (const float*)d_in[18];
    const float* Wu1 = (const float*)d_in[19]; const float* bu1 = (const float*)d_in[20];
    const float* Wu2 = (const float*)d_in[21]; const float* bu2 = (const float*)d_in[22];
    const float* Wu3 = (const float*)d_in[23]; const float* bu3 = (const float*)d_in[24];

    const int E = in_sizes[3];   // 400000
    const int N = in_sizes[6];   // 50000

    float* e_out = (float*)d_out;
    float* n_out = e_out + (size_t)E * 64;
    float* u_out = n_out + (size_t)N * 64;

    char* wsc = (char*)d_ws;
    float* ecomb_rep = (float*)wsc;
    float* ncomb_rep = (float*)(wsc + 262144);
    float* ecomb     = (float*)(wsc + 524288);
    float* ncomb     = ecomb + 1024;
    char*  wf        = wsc + 532480;
    const char* We1f = wf;          const char* We2f = wf + 65536;
    const char* We3f = wf + 98304;  const char* Wn1f = wf + 114688;
    const char* Wn2f = wf + 163840; const char* Wn3f = wf + 196608;
    int* deg    = (int*)(wsc + 745472);
    int* startA = (int*)(wsc + 945472);
    int* cursor = (int*)(wsc + 1145472);
    int* psum   = (int*)(wsc + 1345472);
    int* elist  = (int*)(wsc + 1346496);
    const size_t WS_NEED = 1346496 + (size_t)E * 4;
    const bool csr = (ws_size >= WS_NEED);

    constexpr int SH_E = 4 * 8192 * 2 + 16384 + 16384 + 4096;   // 69632
    constexpr int SH_N = 3 * 8192 * 2 + 16384 + 16384 + 4096;   // 61440

    hipMemsetAsync(wsc, 0, 524288, stream);
    prep_weights<<<52, 256, 0, stream>>>(We1, We2, We3, Wn1, Wn2, Wn3, wf);

    const int etiles = (E + 63) / 64;
    const int ntiles = (N + 63) / 64;

    if (csr) {
        hipMemsetAsync(deg, 0, (size_t)N * 4, stream);
        const int EB = (E + 255) / 256;
        const int NB = (N + 255) / 256;
        hist_kernel <<<EB, 256, 0, stream>>>(dst, deg, E);
        scanA_kernel<<<NB, 256, 0, stream>>>(deg, psum, N);
        scanB_kernel<<<1, 256, 0, stream>>>(psum, NB);
        scanC_kernel<<<NB, 256, 0, stream>>>(deg, psum, startA, cursor, N);
        fill_kernel <<<EB, 256, 0, stream>>>(dst, cursor, elist, E);

        auto ek = mlp_col_kernel<4, true, false, false>;
        auto nk = mlp_col_kernel<3, false, false, true>;
        hipFuncSetAttribute((const void*)ek,
                            hipFuncAttributeMaxDynamicSharedMemorySize, SH_E);
        hipFuncSetAttribute((const void*)nk,
                            hipFuncAttributeMaxDynamicSharedMemorySize, SH_N);

        ek<<<512, 512, SH_E, stream>>>(
            edge_feat, node_feat, g_repr, src, dst, e2g,
            nullptr, nullptr, nullptr, nullptr,
            We1f, We2f, We3f, be1, be2, be3,
            e_out, nullptr, ecomb_rep, E, etiles);
        nk<<<512, 512, SH_N, stream>>>(
            node_feat, nullptr, g_repr, nullptr, nullptr, n2g,
            startA, cursor, elist, e_out,
            Wn1f, Wn2f, Wn3f, bn1, bn2, bn3,
            n_out, nullptr, ncomb_rep, N, ntiles);
    } else {
        hipMemsetAsync(n_out, 0, (size_t)N * 64 * sizeof(float), stream);
        auto ek = mlp_col_kernel<4, true, true, false>;
        auto nk = mlp_col_kernel<3, false, false, false>;
        hipFuncSetAttribute((const void*)ek,
                            hipFuncAttributeMaxDynamicSharedMemorySize, SH_E);
        hipFuncSetAttribute((const void*)nk,
                            hipFuncAttributeMaxDynamicSharedMemorySize, SH_N);
        ek<<<512, 512, SH_E, stream>>>(
            edge_feat, node_feat, g_repr, src, dst, e2g,
            nullptr, nullptr, nullptr, nullptr,
            We1f, We2f, We3f, be1, be2, be3,
            e_out, n_out, ecomb_rep, E, etiles);
        nk<<<512, 512, SH_N, stream>>>(
            node_feat, n_out, g_repr, nullptr, nullptr, n2g,
            nullptr, nullptr, nullptr, nullptr,
            Wn1f, Wn2f, Wn3f, bn1, bn2, bn3,
            n_out, nullptr, ncomb_rep, N, ntiles);
    }

    reduce_rep_kernel<<<8, 256, 0, stream>>>(ecomb_rep, ecomb);
    u_kernel<<<1, 256, 0, stream>>>(ncomb, ecomb, g_repr,
                                    Wu1, bu1, Wu2, bu2, Wu3, bu3, u_out);
}

// Round 8
// 295.469 us; speedup vs baseline: 1.6055x; 1.6055x over previous
//
#include <hip/hip_runtime.h>
#include <cstdint>

// GraphNets v8 = v6 (weights-in-LDS, reg-gather) + MFMA-based comb reduction
// (replaces 64 LDS-atomic adds per output row with 4 MFMAs per wave-tile).
// mfma_f32_16x16x32_bf16: A lane l: row=l&15, k=(l>>4)*8+j ; B: col=l&15, same k
// C/D: col=lane&15, row=(lane>>4)*4+reg   [verified v2-v7]

typedef short short8 __attribute__((ext_vector_type(8)));
typedef float f32x4 __attribute__((ext_vector_type(4)));

#define MFMA16(a, b, c) __builtin_amdgcn_mfma_f32_16x16x32_bf16(a, b, c, 0, 0, 0)

__device__ __forceinline__ short f2bf(float x) {
    union { __bf16 b; short s; } u; u.b = (__bf16)x; return u.s;
}
__device__ __forceinline__ short8 pack8(float4 lo, float4 hi) {
    short8 r;
    r[0] = f2bf(lo.x); r[1] = f2bf(lo.y); r[2] = f2bf(lo.z); r[3] = f2bf(lo.w);
    r[4] = f2bf(hi.x); r[5] = f2bf(hi.y); r[6] = f2bf(hi.z); r[7] = f2bf(hi.w);
    return r;
}
__device__ __forceinline__ short8 pack8v(f32x4 lo, f32x4 hi) {
    short8 r;
    r[0] = f2bf(lo[0]); r[1] = f2bf(lo[1]); r[2] = f2bf(lo[2]); r[3] = f2bf(lo[3]);
    r[4] = f2bf(hi[0]); r[5] = f2bf(hi[1]); r[6] = f2bf(hi[2]); r[7] = f2bf(hi[3]);
    return r;
}

// ---------------------------------------------------------------------------
// Weight prep (verified v2-v7). edge = We1|We2|We3 (112KB at 0),
// node = Wn1|Wn2|Wn3 (96KB at 114688).
// ---------------------------------------------------------------------------
__global__ __launch_bounds__(256)
void prep_weights(const float* __restrict__ We1, const float* __restrict__ We2,
                  const float* __restrict__ We3, const float* __restrict__ Wn1,
                  const float* __restrict__ Wn2, const float* __restrict__ Wn3,
                  char* __restrict__ out)
{
    const int fg = blockIdx.x * 4 + (threadIdx.x >> 6);
    if (fg >= 208) return;
    const int lane = threadIdx.x & 63;
    const float* W; int Ncols, f; size_t obase;
    if      (fg < 64)  { W = We1; Ncols = 128; f = fg;       obase = 0;      }
    else if (fg < 96)  { W = We2; Ncols = 128; f = fg - 64;  obase = 65536;  }
    else if (fg < 112) { W = We3; Ncols = 64;  f = fg - 96;  obase = 98304;  }
    else if (fg < 160) { W = Wn1; Ncols = 128; f = fg - 112; obase = 114688; }
    else if (fg < 192) { W = Wn2; Ncols = 128; f = fg - 160; obase = 163840; }
    else               { W = Wn3; Ncols = 64;  f = fg - 192; obase = 196608; }
    const int NF = Ncols >> 4;
    const int kf = f / NF, nf = f - kf * NF;
    const int k0 = kf * 32 + (lane >> 4) * 8;
    const int col = nf * 16 + (lane & 15);
    union { short s[8]; uint4 u; } pk;
#pragma unroll
    for (int j = 0; j < 8; ++j) pk.s[j] = f2bf(W[(size_t)(k0 + j) * Ncols + col]);
    *(uint4*)(out + obase + ((size_t)f * 64 + lane) * 16) = pk.u;
}

// ---------------------------------------------------------------------------
// CSR build (verified v4)
// ---------------------------------------------------------------------------
__global__ __launch_bounds__(256)
void hist_kernel(const int* __restrict__ dst, int* __restrict__ deg, int E)
{
    const int i = blockIdx.x * 256 + threadIdx.x;
    if (i < E) atomicAdd(&deg[dst[i]], 1);
}
__global__ __launch_bounds__(256)
void scanA_kernel(const int* __restrict__ deg, int* __restrict__ psum, int n)
{
    __shared__ int red[256];
    const int t = threadIdx.x;
    const int i = blockIdx.x * 256 + t;
    red[t] = (i < n) ? deg[i] : 0;
    __syncthreads();
    for (int s = 128; s > 0; s >>= 1) {
        if (t < s) red[t] += red[t + s];
        __syncthreads();
    }
    if (t == 0) psum[blockIdx.x] = red[0];
}
__global__ __launch_bounds__(256)
void scanB_kernel(int* __restrict__ psum, int nb)
{
    __shared__ int s[256];
    const int t = threadIdx.x;
    const int v0 = (t < nb) ? psum[t] : 0;
    s[t] = v0;
    __syncthreads();
    for (int d = 1; d < 256; d <<= 1) {
        const int v = (t >= d) ? s[t - d] : 0;
        __syncthreads();
        s[t] += v;
        __syncthreads();
    }
    if (t < nb) psum[t] = s[t] - v0;
}
__global__ __launch_bounds__(256)
void scanC_kernel(const int* __restrict__ deg, const int* __restrict__ psum,
                  int* __restrict__ start, int* __restrict__ cursor, int n)
{
    __shared__ int s[256];
    const int t = threadIdx.x;
    const int i = blockIdx.x * 256 + t;
    const int v0 = (i < n) ? deg[i] : 0;
    s[t] = v0;
    __syncthreads();
    for (int d = 1; d < 256; d <<= 1) {
        const int v = (t >= d) ? s[t - d] : 0;
        __syncthreads();
        s[t] += v;
        __syncthreads();
    }
    const int ex = s[t] - v0 + psum[blockIdx.x];
    if (i < n) { start[i] = ex; cursor[i] = ex; }
}
__global__ __launch_bounds__(256)
void fill_kernel(const int* __restrict__ dst, int* __restrict__ cursor,
                 int* __restrict__ elist, int E)
{
    const int i = blockIdx.x * 256 + threadIdx.x;
    if (i < E) {
        const int d = dst[i];
        const int p = atomicAdd(&cursor[d], 1);
        elist[p] = i;
    }
}

// ---------------------------------------------------------------------------
// Fused MLP, weights resident in LDS (v6 structure). 512 thr = 8 waves,
// 1 block/CU, grid-stride 128-row tiles; wave owns 16 rows.
// comb: per-wave one-hot MFMA into registers (NO per-row atomics).
// ---------------------------------------------------------------------------
template <int NQ, bool IS_EDGE, bool MSG_ATOMIC, bool GATHER>
__global__ __launch_bounds__(512, 2)
void mlp_fused_kernel(const float* __restrict__ feat0,
                      const float* feat1,
                      const float* __restrict__ gr,
                      const int* __restrict__ srcIdx, const int* __restrict__ dstIdx,
                      const int* __restrict__ seg,
                      const int* __restrict__ gstart, const int* __restrict__ gend,
                      const int* __restrict__ elist,  const float* __restrict__ gsrc,
                      const char* __restrict__ Wsrc,
                      const float* __restrict__ b1, const float* __restrict__ b2,
                      const float* __restrict__ b3,
                      float* out, float* msgs_out, float* comb_rep,
                      int M, int ntiles)
{
    constexpr int KF1   = NQ * 2;                  // layer-1 kf count
    constexpr int NFRAG = KF1 * 8 + 32 + 16;       // W1 + W2 + W3 frags
    constexpr int HOFF  = NFRAG * 1024;
    extern __shared__ char lds[];
    float* combs = (float*)(lds + HOFF + 8 * 4096);

    const int t    = threadIdx.x;
    const int lane = t & 63;
    const int w    = t >> 6;
    const int l15  = lane & 15;
    const int l4   = lane >> 4;
    char* Hs = lds + HOFF + w * 4096;              // wave-private 4KB (h1/h2/P)

    // ---- stage all weight fragments to LDS once; zero comb ----
    for (int f = t; f < NFRAG * 64; f += 512)
        *(uint4*)(lds + (size_t)f * 16) = *(const uint4*)(Wsrc + (size_t)f * 16);
    for (int i = t; i < 1024; i += 512) combs[i] = 0.f;
    __syncthreads();

    const char* W1l = lds;
    const char* W2l = lds + (size_t)KF1 * 8 * 1024;
    const char* W3l = W2l + 32 * 1024;

    // per-wave comb accumulators: acc_comb[nf][q] -> graph g=l4*4+q, col nf*16+l15
    f32x4 acc_comb[4];
#pragma unroll
    for (int nf = 0; nf < 4; ++nf) acc_comb[nf] = f32x4{0.f, 0.f, 0.f, 0.f};

    for (int tile = blockIdx.x; tile < ntiles; tile += gridDim.x) {
        const int base = tile * 128 + w * 16;
        const int row  = base + l15;               // this lane's source row
        const bool valid = row < M;

        // ---- indices ----
        int isrc = 0, idst = 0, ig = 0;
        if (valid) {
            if (IS_EDGE) { isrc = srcIdx[row]; idst = dstIdx[row]; ig = seg[row]; }
            else         { ig = seg[row]; }
        }

        // ---- gather X straight into A-fragment registers ----
        short8 xf[KF1];
#pragma unroll
        for (int kf = 0; kf < KF1; ++kf) {
            const int c = kf >> 1;
            if (GATHER && c == 1) continue;        // msgs handled below
            float4 lo = make_float4(0.f, 0.f, 0.f, 0.f), hi = lo;
            if (valid) {
                const float* p;
                if (IS_EDGE) {
                    p = (c == 0) ? feat0 + (size_t)row  * 64
                      : (c == 1) ? feat1 + (size_t)isrc * 64
                      : (c == 2) ? feat1 + (size_t)idst * 64
                      :            gr    + (size_t)ig   * 64;
                } else if (GATHER) {
                    p = (c == 0) ? feat0 + (size_t)row * 64
                      :            gr    + (size_t)ig  * 64;
                } else {
                    p = (c == 0) ? feat0 + (size_t)row * 64
                      : (c == 1) ? feat1 + (size_t)row * 64
                      :            gr    + (size_t)ig  * 64;
                }
                const int koff = (kf & 1) * 32 + l4 * 8;
                lo = *(const float4*)(p + koff);
                hi = *(const float4*)(p + koff + 4);
            }
            xf[kf] = pack8(lo, hi);
        }
        if constexpr (GATHER) {
            f32x4 m0 = {0,0,0,0}, m1 = m0, m2 = m0, m3 = m0;
            if (valid) {
                const int s0 = gstart[row], e0 = gend[row];
                for (int j = s0; j < e0; ++j) {
                    const float* er = gsrc + (size_t)elist[j] * 64 + l4 * 8;
                    m0 += *(const f32x4*)(er);
                    m1 += *(const f32x4*)(er + 4);
                    m2 += *(const f32x4*)(er + 32);
                    m3 += *(const f32x4*)(er + 36);
                }
            }
            xf[2] = pack8v(m0, m1);
            xf[3] = pack8v(m2, m3);
        }

        // ---- layer 1 ----
        f32x4 acc[8];
#pragma unroll
        for (int nf = 0; nf < 8; ++nf) {
            const float bv = b1[nf * 16 + l15];
            acc[nf] = f32x4{bv, bv, bv, bv};
        }
#pragma unroll
        for (int kf = 0; kf < KF1; ++kf) {
#pragma unroll
            for (int nf = 0; nf < 8; ++nf) {
                short8 bw = *(const short8*)(W1l + ((size_t)(kf * 8 + nf) * 64 + lane) * 16);
                acc[nf] = MFMA16(xf[kf], bw, acc[nf]);
            }
        }
        // relu -> h1 (wave-private swizzle, stride 256B)
#pragma unroll
        for (int nf = 0; nf < 8; ++nf)
#pragma unroll
            for (int q = 0; q < 4; ++q) {
                const int rowL = l4 * 4 + q;
                const int slot = (nf * 2 + (l15 >> 3)) ^ (rowL & 7);
                *(short*)(Hs + rowL * 256 + slot * 16 + (l15 & 7) * 2) =
                    f2bf(fmaxf(acc[nf][q], 0.f));
            }

        // ---- layer 2 ----
        f32x4 acc2[8];
#pragma unroll
        for (int nf = 0; nf < 8; ++nf) {
            const float bv = b2[nf * 16 + l15];
            acc2[nf] = f32x4{bv, bv, bv, bv};
        }
#pragma unroll
        for (int kf = 0; kf < 4; ++kf) {
            const int slot = (kf * 4 + l4) ^ (l15 & 7);
            short8 a = *(short8*)(Hs + l15 * 256 + slot * 16);
#pragma unroll
            for (int nf = 0; nf < 8; ++nf) {
                short8 bw = *(const short8*)(W2l + ((size_t)(kf * 8 + nf) * 64 + lane) * 16);
                acc2[nf] = MFMA16(a, bw, acc2[nf]);
            }
        }
        // relu -> h2 (aliases h1; in-wave DS order makes this safe)
#pragma unroll
        for (int nf = 0; nf < 8; ++nf)
#pragma unroll
            for (int q = 0; q < 4; ++q) {
                const int rowL = l4 * 4 + q;
                const int slot = (nf * 2 + (l15 >> 3)) ^ (rowL & 7);
                *(short*)(Hs + rowL * 256 + slot * 16 + (l15 & 7) * 2) =
                    f2bf(fmaxf(acc2[nf][q], 0.f));
            }

        // ---- layer 3 ----
        f32x4 acc3[4];
#pragma unroll
        for (int nf = 0; nf < 4; ++nf) {
            const float bv = b3[nf * 16 + l15];
            acc3[nf] = f32x4{bv, bv, bv, bv};
        }
#pragma unroll
        for (int kf = 0; kf < 4; ++kf) {
            const int slot = (kf * 4 + l4) ^ (l15 & 7);
            short8 a = *(short8*)(Hs + l15 * 256 + slot * 16);
#pragma unroll
            for (int nf = 0; nf < 4; ++nf) {
                short8 bw = *(const short8*)(W3l + ((size_t)(kf * 4 + nf) * 64 + lane) * 16);
                acc3[nf] = MFMA16(a, bw, acc3[nf]);
            }
        }

        // ---- comb via one-hot MFMA (replaces per-row LDS atomics) ----
        // Stage acc3 bf16 into P (aliases Hs), COLUMN-major P[col][row]:
        // lane owns col = nf*16+l15, rows l4*4+{0..3}. All layer-3 reads of Hs
        // precede these writes in-wave -> safe alias.
#pragma unroll
        for (int nf = 0; nf < 4; ++nf) {
            union { unsigned u; short s[2]; } p01, p23;
            p01.s[0] = f2bf(acc3[nf][0]); p01.s[1] = f2bf(acc3[nf][1]);
            p23.s[0] = f2bf(acc3[nf][2]); p23.s[1] = f2bf(acc3[nf][3]);
            char* pc = Hs + (nf * 16 + l15) * 64 + l4 * 8;
            *(unsigned*)(pc)     = p01.u;
            *(unsigned*)(pc + 4) = p23.u;
        }
        // One-hot A: lane l -> g=l15, k=l4*8+j. k>=16 (l4>=2) contributes 0,
        // so stale P rows 16..31 (finite bf16 garbage) are multiplied by 0.0.
        short8 oh;
#pragma unroll
        for (int j = 0; j < 8; ++j) {
            short v = 0;
            if (l4 < 2) {
                const int rr = base + l4 * 8 + j;
                if (rr < M && seg[rr] == l15) v = (short)0x3F80;  // bf16 1.0
            }
            oh[j] = v;
        }
#pragma unroll
        for (int nf = 0; nf < 4; ++nf) {
            short8 bp = *(short8*)(Hs + (nf * 16 + l15) * 64 + l4 * 16);
            acc_comb[nf] = MFMA16(oh, bp, acc_comb[nf]);
        }

        // ---- epilogue: store out (+ fallback msgs atomics) ----
#pragma unroll
        for (int q = 0; q < 4; ++q) {
            const int grow = base + l4 * 4 + q;
            if (grow < M) {
                int d = 0;
                if (MSG_ATOMIC) d = dstIdx[grow];
#pragma unroll
                for (int nf = 0; nf < 4; ++nf) {
                    const int col = nf * 16 + l15;
                    const float v = acc3[nf][q];
                    out[(size_t)grow * 64 + col] = v;
                    if constexpr (MSG_ATOMIC)
                        atomicAdd(msgs_out + (size_t)d * 64 + col, v);
                }
            }
        }
    }

    // ---- flush: acc_comb -> block comb (once), then to global replica ----
#pragma unroll
    for (int nf = 0; nf < 4; ++nf)
#pragma unroll
        for (int q = 0; q < 4; ++q)
            atomicAdd(&combs[(l4 * 4 + q) * 64 + nf * 16 + l15], acc_comb[nf][q]);
    __syncthreads();
    float* rep = comb_rep + (size_t)(blockIdx.x & 63) * 1024;
    for (int i = t; i < 1024; i += 512) atomicAdd(rep + i, combs[i]);
}

// ---------------------------------------------------------------------------
__global__ __launch_bounds__(256)
void reduce_rep_kernel(const float* __restrict__ rep, float* __restrict__ outv)
{
    const int s = blockIdx.x * 256 + threadIdx.x;   // 0..2047
    const int arr = s >> 10, idx = s & 1023;
    const float* p = rep + (size_t)arr * 65536 + idx;
    float v = 0.f;
#pragma unroll 8
    for (int r = 0; r < 64; ++r) v += p[(size_t)r * 1024];
    outv[s] = v;
}

// ---------------------------------------------------------------------------
__global__ __launch_bounds__(256)
void u_kernel(const float* __restrict__ ncomb, const float* __restrict__ ecomb,
              const float* __restrict__ gr,
              const float* __restrict__ W1, const float* __restrict__ b1,
              const float* __restrict__ W2, const float* __restrict__ b2,
              const float* __restrict__ W3, const float* __restrict__ b3,
              float* uout)
{
    __shared__ float X[16 * 192];
    __shared__ float Hs[16 * 128];
    __shared__ float H2s[16 * 128];
    const int t = threadIdx.x;
#pragma unroll
    for (int i = 0; i < 12; ++i) {
        const int idx = i * 256 + t;
        const int g = idx / 192, col = idx % 192;
        float v;
        if      (col < 64)  v = ncomb[g * 64 + col];
        else if (col < 128) v = ecomb[g * 64 + col - 64];
        else                v = gr[g * 64 + col - 128];
        X[idx] = v;
    }
    __syncthreads();
    {
        const int j = t & 127, gb = t >> 7;
        float a[8];
#pragma unroll
        for (int gi = 0; gi < 8; ++gi) a[gi] = b1[j];
        for (int k = 0; k < 192; ++k) {
            const float wv = W1[k * 128 + j];
#pragma unroll
            for (int gi = 0; gi < 8; ++gi) a[gi] += X[(gb + gi * 2) * 192 + k] * wv;
        }
#pragma unroll
        for (int gi = 0; gi < 8; ++gi) Hs[(gb + gi * 2) * 128 + j] = fmaxf(a[gi], 0.f);
    }
    __syncthreads();
    {
        const int j = t & 127, gb = t >> 7;
        float a[8];
#pragma unroll
        for (int gi = 0; gi < 8; ++gi) a[gi] = b2[j];
        for (int k = 0; k < 128; ++k) {
            const float wv = W2[k * 128 + j];
#pragma unroll
            for (int gi = 0; gi < 8; ++gi) a[gi] += Hs[(gb + gi * 2) * 128 + k] * wv;
        }
#pragma unroll
        for (int gi = 0; gi < 8; ++gi) H2s[(gb + gi * 2) * 128 + j] = fmaxf(a[gi], 0.f);
    }
    __syncthreads();
    {
        const int j = t & 63, gb = t >> 6;
        float a[4];
#pragma unroll
        for (int gi = 0; gi < 4; ++gi) a[gi] = b3[j];
        for (int k = 0; k < 128; ++k) {
            const float wv = W3[k * 64 + j];
#pragma unroll
            for (int gi = 0; gi < 4; ++gi) a[gi] += H2s[(gb + gi * 4) * 128 + k] * wv;
        }
#pragma unroll
        for (int gi = 0; gi < 4; ++gi) uout[(gb + gi * 4) * 64 + j] = a[gi];
    }
}

// ---------------------------------------------------------------------------
extern "C" void kernel_launch(void* const* d_in, const int* in_sizes, int n_in,
                              void* d_out, int out_size, void* d_ws, size_t ws_size,
                              hipStream_t stream)
{
    const float* edge_feat = (const float*)d_in[0];
    const float* node_feat = (const float*)d_in[1];
    const float* g_repr    = (const float*)d_in[2];
    const int*   src       = (const int*)d_in[3];
    const int*   dst       = (const int*)d_in[4];
    const int*   e2g       = (const int*)d_in[5];
    const int*   n2g       = (const int*)d_in[6];
    const float* We1 = (const float*)d_in[7];  const float* be1 = (const float*)d_in[8];
    const float* We2 = (const float*)d_in[9];  const float* be2 = (const float*)d_in[10];
    const float* We3 = (const float*)d_in[11]; const float* be3 = (const float*)d_in[12];
    const float* Wn1 = (const float*)d_in[13]; const float* bn1 = (const float*)d_in[14];
    const float* Wn2 = (const float*)d_in[15]; const float* bn2 = (const float*)d_in[16];
    const float* Wn3 = (const float*)d_in[17]; const float* bn3 = (const float*)d_in[18];
    const float* Wu1 = (const float*)d_in[19]; const float* bu1 = (const float*)d_in[20];
    const float* Wu2 = (const float*)d_in[21]; const float* bu2 = (const float*)d_in[22];
    const float* Wu3 = (const float*)d_in[23]; const float* bu3 = (const float*)d_in[24];

    const int E = in_sizes[3];   // 400000
    const int N = in_sizes[6];   // 50000

    float* e_out = (float*)d_out;
    float* n_out = e_out + (size_t)E * 64;
    float* u_out = n_out + (size_t)N * 64;

    char* wsc = (char*)d_ws;
    float* ecomb_rep = (float*)wsc;
    float* ncomb_rep = (float*)(wsc + 262144);
    float* ecomb     = (float*)(wsc + 524288);
    float* ncomb     = ecomb + 1024;
    char*  wf        = wsc + 532480;
    const char* WEsrc = wf;              // We1|We2|We3  (112 KB)
    const char* WNsrc = wf + 114688;     // Wn1|Wn2|Wn3  (96 KB)
    int* deg    = (int*)(wsc + 745472);
    int* startA = (int*)(wsc + 945472);
    int* cursor = (int*)(wsc + 1145472);
    int* psum   = (int*)(wsc + 1345472);
    int* elist  = (int*)(wsc + 1346496);
    const size_t WS_NEED = 1346496 + (size_t)E * 4;
    const bool csr = (ws_size >= WS_NEED);

    constexpr int SH_E = (112 + 32 + 4) * 1024;   // 151552
    constexpr int SH_N = (96 + 32 + 4) * 1024;    // 135168

    hipMemsetAsync(wsc, 0, 524288, stream);
    prep_weights<<<52, 256, 0, stream>>>(We1, We2, We3, Wn1, Wn2, Wn3, wf);

    const int etiles = (E + 127) / 128;
    const int ntiles = (N + 127) / 128;

    if (csr) {
        hipMemsetAsync(deg, 0, (size_t)N * 4, stream);
        const int EB = (E + 255) / 256;
        const int NB = (N + 255) / 256;
        hist_kernel <<<EB, 256, 0, stream>>>(dst, deg, E);
        scanA_kernel<<<NB, 256, 0, stream>>>(deg, psum, N);
        scanB_kernel<<<1, 256, 0, stream>>>(psum, NB);
        scanC_kernel<<<NB, 256, 0, stream>>>(deg, psum, startA, cursor, N);
        fill_kernel <<<EB, 256, 0, stream>>>(dst, cursor, elist, E);

        auto ek = mlp_fused_kernel<4, true, false, false>;
        auto nk = mlp_fused_kernel<3, false, false, true>;
        hipFuncSetAttribute((const void*)ek,
                            hipFuncAttributeMaxDynamicSharedMemorySize, SH_E);
        hipFuncSetAttribute((const void*)nk,
                            hipFuncAttributeMaxDynamicSharedMemorySize, SH_N);

        ek<<<256, 512, SH_E, stream>>>(
            edge_feat, node_feat, g_repr, src, dst, e2g,
            nullptr, nullptr, nullptr, nullptr,
            WEsrc, be1, be2, be3, e_out, nullptr, ecomb_rep, E, etiles);
        nk<<<256, 512, SH_N, stream>>>(
            node_feat, nullptr, g_repr, nullptr, nullptr, n2g,
            startA, cursor, elist, e_out,
            WNsrc, bn1, bn2, bn3, n_out, nullptr, ncomb_rep, N, ntiles);
    } else {
        hipMemsetAsync(n_out, 0, (size_t)N * 64 * sizeof(float), stream);
        auto ek = mlp_fused_kernel<4, true, true, false>;
        auto nk = mlp_fused_kernel<3, false, false, false>;
        hipFuncSetAttribute((const void*)ek,
                            hipFuncAttributeMaxDynamicSharedMemorySize, SH_E);
        hipFuncSetAttribute((const void*)nk,
                            hipFuncAttributeMaxDynamicSharedMemorySize, SH_N);
        ek<<<256, 512, SH_E, stream>>>(
            edge_feat, node_feat, g_repr, src, dst, e2g,
            nullptr, nullptr, nullptr, nullptr,
            WEsrc, be1, be2, be3, e_out, n_out, ecomb_rep, E, etiles);
        nk<<<256, 512, SH_N, stream>>>(
            node_feat, n_out, g_repr, nullptr, nullptr, n2g,
            nullptr, nullptr, nullptr, nullptr,
            WNsrc, bn1, bn2, bn3, n_out, nullptr, ncomb_rep, N, ntiles);
    }

    reduce_rep_kernel<<<8, 256, 0, stream>>>(ecomb_rep, ecomb);
    u_kernel<<<1, 256, 0, stream>>>(ncomb, ecomb, g_repr,
                                    Wu1, bu1, Wu2, bu2, Wu3, bu3, u_out);
}